// Round 17
// baseline (157.372 us; speedup 1.0000x reference)
//
#include <hip/hip_runtime.h>

#define D 16

typedef short bf16x8 __attribute__((ext_vector_type(8)));
typedef float f32x16 __attribute__((ext_vector_type(16)));
typedef float v2f __attribute__((ext_vector_type(2)));

// ---- DPP helpers (wave64), verified rounds 8-15 ----
template<int CTRL, int RMASK, bool BC>
__device__ __forceinline__ float dpp_add(float x) {
    int t = __builtin_amdgcn_update_dpp(0, __float_as_int(x), CTRL, RMASK, 0xF, BC);
    return x + __int_as_float(t);
}
// full 64-lane inclusive scan (fallback kernel)
__device__ __forceinline__ float wave_iscan(float x) {
    x = dpp_add<0x111, 0xF, true >(x);   // row_shr:1
    x = dpp_add<0x112, 0xF, true >(x);   // row_shr:2
    x = dpp_add<0x114, 0xF, true >(x);   // row_shr:4
    x = dpp_add<0x118, 0xF, true >(x);   // row_shr:8
    x = dpp_add<0x142, 0xA, false>(x);   // row_bcast:15
    x = dpp_add<0x143, 0xC, false>(x);   // row_bcast:31
    return x;
}
// 32-lane-confined inclusive scan: lanes 0-31 and 32-63 fully independent
__device__ __forceinline__ float half_iscan(float x) {
    x = dpp_add<0x111, 0xF, true >(x);   // row_shr:1
    x = dpp_add<0x112, 0xF, true >(x);   // row_shr:2
    x = dpp_add<0x114, 0xF, true >(x);   // row_shr:4
    x = dpp_add<0x118, 0xF, true >(x);   // row_shr:8 (16-lane prefix)
    x = dpp_add<0x142, 0xA, false>(x);   // row_bcast:15 -> 16->32 stitch/half
    return x;
}

// f32 -> bf16 round-to-nearest-even
__device__ __forceinline__ short f2bf(float f) {
    unsigned u = __float_as_uint(f);
    unsigned r = u + 0x7FFFu + ((u >> 16) & 1u);
    return (short)(r >> 16);
}

// ---------------- prep: bf16 diff tables (r14, verified) ----------------
// T layout: [src (0=X,1=Y)][a][row 0..511][k 0..15] bf16 (row 511 zeroed).
__global__ void sig_prep_kernel(const float* __restrict__ X,
                                const float* __restrict__ Y,
                                unsigned short* __restrict__ T) {
    const int blk = blockIdx.x;            // 256 blocks
    const int src = blk >> 7;
    const int a   = blk & 127;
    const float* P = (src ? Y : X) + (size_t)a * 512 * D;
    unsigned short* O = T + (size_t)blk * 512 * D;
    for (int e = threadIdx.x; e < 511 * D; e += 256)
        O[e] = (unsigned short)f2bf(P[e + D] - P[e]);
    if (threadIdx.x < D) O[511 * D + threadIdx.x] = 0;
}

// ---------------- main: half-wave dual-problem ----------------
// Lanes 0-31 = problem idx0, lanes 32-63 = problem idx1. Each lane owns 16
// columns (j = 16q..16q+15, q = l&31). One instruction stream advances BOTH
// problems (SIMD packing -> 2x throughput, zero register duplication).
// GEMM: r13-verified 16-row-tile scheme (32x32x16 MFMA, acc half stored per
// phase, recompute), write swizzle verbatim; fragments stream from the bf16
// tables (ring-4). Scan: r11 deferred-base algebra with 16-col lanes and the
// 5-stage half-confined DPP scan.
__global__ __launch_bounds__(64, 1)
void sig_pde_half2_kernel(const unsigned short* __restrict__ T,
                          float* __restrict__ out) {
    __shared__ float sinc[2 * 16 * 512];    // 64 KB: one 16-row tile/problem

    const int bid  = blockIdx.x;            // 192 blocks
    const int idx0 = 2 * bid, idx1 = idx0 + 1;
    const int pair0 = idx0 >> 7, a0 = idx0 & 127;
    const int pair1 = idx1 >> 7, a1 = idx1 & 127;

    const unsigned short* TX = T;
    const unsigned short* TY = T + (size_t)128 * 512 * D;
    const unsigned short* tp0 = ((pair0 == 1) ? TY : TX) + (size_t)a0 * 512 * D;
    const unsigned short* tq0 = ((pair0 == 0) ? TX : TY) + (size_t)a0 * 512 * D;
    const unsigned short* tp1 = ((pair1 == 1) ? TY : TX) + (size_t)a1 * 512 * D;
    const unsigned short* tq1 = ((pair1 == 0) ? TX : TY) + (size_t)a1 * 512 * D;

    const int l  = threadIdx.x;
    const int lm = l & 31;
    const int kh = l >> 5;                  // MFMA K-half AND problem-in-wave
    const int l7 = l & 7;
    const int q  = l & 31;                  // lane-in-half (column owner)
    const bool q0 = (q == 0);

    // 16B fragment load from a diff table (row clamped at 0)
    auto loadF = [&](const unsigned short* t, int r) -> bf16x8 {
        int ii = r < 0 ? 0 : r;
        return *(const bf16x8*)(t + (size_t)ii * D + kh * 8);
    };

    // GEMM write bases (r13 swizzle verbatim); tile h at +8192 floats
    float* wb0 = sinc + kh * 2048 + (lm & ~7);
    float* wb1 = sinc + 8192 + kh * 2048 + (lm & ~7);

    // read addresses: lane reads cols 16q+m; stored pos (write-swizzle
    // inverse) = 16q + (m&8) + (((m&7)+(q>>1))&7). 8 low offsets; m>=8: +32B.
    unsigned ea8[8];
    #pragma unroll
    for (int m = 0; m < 8; ++m)
        ea8[m] = (unsigned)(kh * 32768 + (16 * q + ((m + (q >> 1)) & 7)) * 4);

    // ---- scan state (one problem per half-wave; NOT duplicated) ----
    float s[16];
    #pragma unroll
    for (int m = 0; m < 16; ++m) s[m] = 0.0f;   // K[0][j] = 1 = B + 0
    float B = 1.0f;
    v2f gh[16];
    float eA[16], eB[16];

    const f32x16 accC = {-1.f,-1.f,-1.f,-1.f,-1.f,-1.f,-1.f,-1.f,
                         -1.f,-1.f,-1.f,-1.f,-1.f,-1.f,-1.f,-1.f};

#define PREF(BUF, RB) do {                                                    \
        const char* pb_ = (const char*)sinc + (RB);                           \
        _Pragma("unroll")                                                     \
        for (int m_ = 0; m_ < 16; ++m_)                                       \
            BUF[m_] = *(const float*)(pb_ + ea8[m_ & 7] + (m_ & 8) * 4);      \
    } while (0)

#define TOUCH(BUF) do { float tt_ = BUF[15];                                  \
        asm volatile("" : "+v"(tt_)); BUF[15] = tt_; } while (0)

#define GH16(E) do {                                                          \
        float gp_ = E[0] + 1.0f;  gp_ = q0 ? 0.0f : gp_;                      \
        float gc_ = q0 ? 0.0f : s[0];                                         \
        gh[0][0] = gp_; gh[0][1] = gc_;                                       \
        _Pragma("unroll")                                                     \
        for (int m_ = 1; m_ < 16; ++m_) {                                     \
            v2f pc_;                                                          \
            pc_[0] = E[m_] + 1.0f;                                            \
            pc_[1] = fmaf(s[m_ - 1], E[m_], s[m_]);                          \
            gh[m_] = gh[m_ - 1] + pc_;                                        \
        }                                                                     \
    } while (0)

#define SF16() do {                                                           \
        _Pragma("unroll")                                                     \
        for (int m_ = 0; m_ < 16; ++m_)                                       \
            s[m_] = fmaf(B, gh[m_][0], gh[m_][1]);                            \
    } while (0)

#define DSTEP(EN, EP, RP) do {                                                \
        TOUCH(EN);                                                            \
        SF16();                                                               \
        float S_ = s[15];                                                     \
        float W_ = half_iscan(S_);                                            \
        PREF(EP, RP);                                                         \
        GH16(EN);                                                             \
        B = 1.0f + (W_ - S_);                                                 \
    } while (0)

#define DTAIL() do {                                                          \
        SF16();                                                               \
        float S_ = s[15];                                                     \
        float W_ = half_iscan(S_);                                            \
        B = 1.0f + (W_ - S_);                                                 \
    } while (0)

// scan tile rows R0..15 (R0 literal 0/1); r13 sequencing verbatim
#define SCANP(R0) do {                                                        \
        PREF(eA, (R0) * 2048);                                                \
        GH16(eA);                                                             \
        PREF(eB, ((R0) + 1) * 2048);                                          \
        _Pragma("unroll")                                                     \
        for (int r_ = (R0); r_ <= 14; ++r_) {                                 \
            const int rp_ = (r_ + 2 <= 15 ? r_ + 2 : 15) * 2048;              \
            if (((r_ - (R0)) & 1) == 0) DSTEP(eB, eA, rp_);                   \
            else                        DSTEP(eA, eB, rp_);                   \
        }                                                                     \
        DTAIL();                                                              \
    } while (0)

// GEMM for one problem, acc half H (literal): 16 MFMA, ring-4 frag stream
#define GEMMP(TQ, ACUR, WB, H) do {                                           \
        bf16x8 F_[4];                                                         \
        _Pragma("unroll")                                                     \
        for (int n_ = 0; n_ < 4; ++n_) F_[n_] = loadF(TQ, 32 * n_ + lm - 1);  \
        _Pragma("unroll")                                                     \
        for (int n_ = 0; n_ < 16; ++n_) {                                     \
            f32x16 c_ = __builtin_amdgcn_mfma_f32_32x32x16_bf16(ACUR, F_[n_ & 3], accC, 0, 0, 0); \
            if (n_ + 4 < 16) F_[n_ & 3] = loadF(TQ, 32 * (n_ + 4) + lm - 1);  \
            float* g_ = (WB) + 32 * n_ + ((l7 + n_) & 7);                     \
            _Pragma("unroll")                                                 \
            for (int r_ = 0; r_ < 8; ++r_)                                    \
                g_[(r_ & 3) * 512 + (r_ >> 2) * 4096] = c_[8 * (H) + r_];     \
        }                                                                     \
    } while (0)

    bf16x8 Ac0 = loadF(tp0, lm - 1);
    bf16x8 Ac1 = loadF(tp1, lm - 1);

    for (int b = 0; b < 16; ++b) {
        GEMMP(tq0, Ac0, wb0, 0);
        GEMMP(tq1, Ac1, wb1, 0);
        if (b == 0) SCANP(1);          // skip grid row 0
        else        SCANP(0);
        GEMMP(tq0, Ac0, wb0, 1);
        GEMMP(tq1, Ac1, wb1, 1);
        if (b < 15) {
            Ac0 = loadF(tp0, 32 * (b + 1) + lm - 1);
            Ac1 = loadF(tp1, 32 * (b + 1) + lm - 1);
        }
        SCANP(0);
    }

#undef GEMMP
#undef SCANP
#undef DTAIL
#undef DSTEP
#undef SF16
#undef GH16
#undef TOUCH
#undef PREF

    // K[511][511]: col 511 = lane q=31 of each half, m=15
    if (l == 31) out[idx0] = B + s[15];
    if (l == 63) out[idx1] = B + s[15];
}

// ---------------- fallback: r12 single-problem kernel (proven ~93 us) ------
__global__ __launch_bounds__(64, 1)
void sig_pde_single_kernel(const float* __restrict__ X, const float* __restrict__ Y,
                           float* __restrict__ out) {
    __shared__ float sinc[32 * 512];

    const int idx  = blockIdx.x;
    const int pair = idx >> 7;
    const int a    = idx & 127;
    const float* Pp = (pair == 1) ? Y : X;
    const float* Qp = (pair == 0) ? X : Y;
    const float* prow = Pp + (size_t)a * 512 * D;
    const float* qrow = Qp + (size_t)a * 512 * D;

    const int l  = threadIdx.x;
    const int lm = l & 31;
    const int kh = l >> 5;
    const int d0 = kh * 8;
    const bool lane0 = (l == 0);

    bf16x8 Bf[16];
    #pragma unroll
    for (int n = 0; n < 16; ++n) {
        int jj = 32 * n + lm - 1;
        if (jj < 0) jj = 0;
        const float4* y1 = (const float4*)(qrow + (size_t)(jj + 1) * D + d0);
        const float4* y0 = (const float4*)(qrow + (size_t)jj * D + d0);
        float4 h1 = y1[0], h0 = y0[0], g1 = y1[1], g0 = y0[1];
        bf16x8 f;
        f[0] = f2bf(h1.x - h0.x); f[1] = f2bf(h1.y - h0.y);
        f[2] = f2bf(h1.z - h0.z); f[3] = f2bf(h1.w - h0.w);
        f[4] = f2bf(g1.x - g0.x); f[5] = f2bf(g1.y - g0.y);
        f[6] = f2bf(g1.z - g0.z); f[7] = f2bf(g1.w - g0.w);
        Bf[n] = f;
    }

    auto loadA = [&](int b) -> bf16x8 {
        int ii = 32 * b + lm - 1;
        if (ii < 0) ii = 0;
        const float4* x1 = (const float4*)(prow + (size_t)(ii + 1) * D + d0);
        const float4* x0 = (const float4*)(prow + (size_t)ii * D + d0);
        float4 h1 = x1[0], h0 = x0[0], g1 = x1[1], g0 = x0[1];
        bf16x8 f;
        f[0] = f2bf(h1.x - h0.x); f[1] = f2bf(h1.y - h0.y);
        f[2] = f2bf(h1.z - h0.z); f[3] = f2bf(h1.w - h0.w);
        f[4] = f2bf(g1.x - g0.x); f[5] = f2bf(g1.y - g0.y);
        f[6] = f2bf(g1.z - g0.z); f[7] = f2bf(g1.w - g0.w);
        return f;
    };

    const int rot = (l >> 2) & 7;
    float* wbase = sinc + kh * 2048;

    int ea4[8];
    #pragma unroll
    for (int m = 0; m < 8; ++m) ea4[m] = (8 * l + ((m + rot) & 7)) * 4;

    float s[8];
    #pragma unroll
    for (int m = 0; m < 8; ++m) s[m] = 0.0f;
    float B = 1.0f;

    v2f ghA[8], ghB[8];
    float eA[8], eB[8];

    const f32x16 accC = {-1.f,-1.f,-1.f,-1.f,-1.f,-1.f,-1.f,-1.f,
                         -1.f,-1.f,-1.f,-1.f,-1.f,-1.f,-1.f,-1.f};

#define PREF(BUF, RB) do {                                                    \
        const char* pb_ = (const char*)sinc + (RB);                           \
        _Pragma("unroll")                                                     \
        for (int m_ = 0; m_ < 8; ++m_)                                        \
            BUF[m_] = *(const float*)(pb_ + ea4[m_]);                         \
    } while (0)

#define TOUCH(BUF) do { float tt_ = BUF[7];                                   \
        asm volatile("" : "+v"(tt_)); BUF[7] = tt_; } while (0)

#define GHBUILD(GH, E) do {                                                   \
        float p0_ = E[0] + 1.0f;  p0_ = lane0 ? 0.0f : p0_;                   \
        float c0_ = lane0 ? 0.0f : s[0];                                      \
        GH[0][0] = p0_; GH[0][1] = c0_;                                       \
        _Pragma("unroll")                                                     \
        for (int m_ = 1; m_ < 8; ++m_) {                                      \
            v2f pc_;                                                          \
            pc_[0] = E[m_] + 1.0f;                                            \
            pc_[1] = fmaf(s[m_ - 1], E[m_], s[m_]);                          \
            GH[m_] = GH[m_ - 1] + pc_;                                        \
        }                                                                     \
    } while (0)

#define SFMA(GH) do {                                                         \
        _Pragma("unroll")                                                     \
        for (int m_ = 0; m_ < 8; ++m_)                                        \
            s[m_] = fmaf(B, GH[m_][0], GH[m_][1]);                            \
    } while (0)

#define STEPROW(GHC, EP, RP, EN, GHN) do {                                    \
        TOUCH(EN);                                                            \
        SFMA(GHC);                                                            \
        float S_ = s[7];                                                      \
        float W_ = wave_iscan(S_);                                            \
        PREF(EP, RP);                                                         \
        GHBUILD(GHN, EN);                                                     \
        B = 1.0f + (W_ - S_);                                                 \
    } while (0)

#define TAILROW(GHC) do {                                                     \
        SFMA(GHC);                                                            \
        float S_ = s[7];                                                      \
        float W_ = wave_iscan(S_);                                            \
        B = 1.0f + (W_ - S_);                                                 \
    } while (0)

    bf16x8 Acur = loadA(0);

    for (int b = 0; b < 16; ++b) {
        #pragma unroll
        for (int n = 0; n < 16; ++n) {
            f32x16 acc = __builtin_amdgcn_mfma_f32_32x32x16_bf16(Acur, Bf[n], accC, 0, 0, 0);
            float* p = wbase + 32 * n + (lm & ~7) + (((l & 7) + n) & 7);
            #pragma unroll
            for (int r = 0; r < 16; ++r)
                p[(r & 3) * 512 + (r >> 2) * 4096] = acc[r];
        }
        if (b < 15) Acur = loadA(b + 1);

        if (b == 0) {
            #pragma unroll
            for (int m = 0; m < 8; ++m) { ghA[m][0] = 0.0f; ghA[m][1] = 0.0f; }
            PREF(eB, 2048);
        } else {
            PREF(eA, 0);
            PREF(eB, 2048);
            GHBUILD(ghA, eA);
        }
        for (int i = 0; i < 15; ++i) {
            const int rp1 = (2 * i + 2) * 2048;
            const int rp2 = (2 * i + 3) * 2048;
            STEPROW(ghA, eA, rp1, eB, ghB);
            STEPROW(ghB, eB, rp2, eA, ghA);
        }
        STEPROW(ghA, eA, 31 * 2048, eB, ghB);
        TAILROW(ghB);
    }

#undef TAILROW
#undef STEPROW
#undef SFMA
#undef GHBUILD
#undef TOUCH
#undef PREF

    if (l == 63) out[idx] = B + s[7];
}

__global__ void sig_reduce_kernel(const float* __restrict__ ws,
                                  float* __restrict__ out) {
    const int a = threadIdx.x;  // 128 threads
    float v = ws[a] + ws[128 + a] - 2.0f * ws[256 + a];
    #pragma unroll
    for (int off = 32; off >= 1; off >>= 1) v += __shfl_down(v, off, 64);
    __shared__ float partial[2];
    if ((a & 63) == 0) partial[a >> 6] = v;
    __syncthreads();
    if (a == 0) out[0] = (partial[0] + partial[1]) * (1.0f / 128.0f);
}

extern "C" void kernel_launch(void* const* d_in, const int* in_sizes, int n_in,
                              void* d_out, int out_size, void* d_ws, size_t ws_size,
                              hipStream_t stream) {
    const float* X = (const float*)d_in[0];
    const float* Y = (const float*)d_in[1];
    float* out = (float*)d_out;

    const size_t TBYTES = (size_t)2 * 128 * 512 * D * 2;   // 4 MiB bf16 tables
    if (ws_size >= TBYTES + 2048) {
        unsigned short* T = (unsigned short*)d_ws;
        float* part = (float*)((char*)d_ws + TBYTES);
        sig_prep_kernel<<<dim3(256), dim3(256), 0, stream>>>(X, Y, T);
        sig_pde_half2_kernel<<<dim3(192), dim3(64), 0, stream>>>(T, part);
        sig_reduce_kernel<<<dim3(1), dim3(128), 0, stream>>>(part, out);
    } else {
        float* part = (float*)d_ws;    // 384 floats
        sig_pde_single_kernel<<<dim3(384), dim3(64), 0, stream>>>(X, Y, part);
        sig_reduce_kernel<<<dim3(1), dim3(128), 0, stream>>>(part, out);
    }
}

// Round 18
// 91.056 us; speedup vs baseline: 1.7283x; 1.7283x over previous
//
#include <hip/hip_runtime.h>

#define D 16

typedef short bf16x8 __attribute__((ext_vector_type(8)));
typedef float f32x16 __attribute__((ext_vector_type(16)));
typedef float v2f __attribute__((ext_vector_type(2)));

// ---- DPP helpers (wave64), verified rounds 8-17 ----
template<int CTRL, int RMASK, bool BC>
__device__ __forceinline__ float dpp_add(float x) {
    int t = __builtin_amdgcn_update_dpp(0, __float_as_int(x), CTRL, RMASK, 0xF, BC);
    return x + __int_as_float(t);
}
__device__ __forceinline__ float wave_iscan(float x) {
    x = dpp_add<0x111, 0xF, true >(x);   // row_shr:1
    x = dpp_add<0x112, 0xF, true >(x);   // row_shr:2
    x = dpp_add<0x114, 0xF, true >(x);   // row_shr:4
    x = dpp_add<0x118, 0xF, true >(x);   // row_shr:8
    x = dpp_add<0x142, 0xA, false>(x);   // row_bcast:15
    x = dpp_add<0x143, 0xC, false>(x);   // row_bcast:31
    return x;
}

// f32 -> bf16 round-to-nearest-even
__device__ __forceinline__ short f2bf(float f) {
    unsigned u = __float_as_uint(f);
    unsigned r = u + 0x7FFFu + ((u >> 16) & 1u);
    return (short)(r >> 16);
}

// One wave per (pair,batch); r15 structure (91 us) with the scan row body
// HAND-SCHEDULED: each DPP of the lane-iscan is issued, a slot of
// independent work (SFMA batch / pc builds / gh links / pinned ds_reads)
// fills its latency, then the dependent add executes. sched_barrier(0)
// pins the slot boundaries (CDNA waves issue in order; the default emitted
// order serializes the 12-op DPP chain - hypothesis H1).
__global__ __launch_bounds__(64, 1)
void sig_pde_kernel(const float* __restrict__ X, const float* __restrict__ Y,
                    float* __restrict__ out) {
    __shared__ float sinc[32 * 512];        // 64 KB (inc-1) block, swizzled

    const int idx  = blockIdx.x;
    const int pair = idx >> 7;              // 0: XX, 1: YY, 2: XY
    const int a    = idx & 127;
    const float* Pp = (pair == 1) ? Y : X;  // row operand (dX)
    const float* Qp = (pair == 0) ? X : Y;  // col operand (dY)
    const float* prow = Pp + (size_t)a * 512 * D;
    const float* qrow = Qp + (size_t)a * 512 * D;

    const int l  = threadIdx.x;
    const int lm = l & 31;
    const int kh = l >> 5;                  // K-half of the fragment
    const int d0 = kh * 8;                  // this lane's dim offset
    const bool lane0 = (l == 0);

    // ---- B fragments: 16 column tiles of dY, resident in registers ----
    bf16x8 Bf[16];
    #pragma unroll
    for (int n = 0; n < 16; ++n) {
        int jj = 32 * n + lm - 1;
        if (jj < 0) jj = 0;                 // col 0 garbage (masked in scan)
        const float4* y1 = (const float4*)(qrow + (size_t)(jj + 1) * D + d0);
        const float4* y0 = (const float4*)(qrow + (size_t)jj * D + d0);
        float4 h1 = y1[0], h0 = y0[0], g1 = y1[1], g0 = y0[1];
        bf16x8 f;
        f[0] = f2bf(h1.x - h0.x); f[1] = f2bf(h1.y - h0.y);
        f[2] = f2bf(h1.z - h0.z); f[3] = f2bf(h1.w - h0.w);
        f[4] = f2bf(g1.x - g0.x); f[5] = f2bf(g1.y - g0.y);
        f[6] = f2bf(g1.z - g0.z); f[7] = f2bf(g1.w - g0.w);
        Bf[n] = f;
    }

    auto loadA = [&](int b) -> bf16x8 {
        int ii = 32 * b + lm - 1;
        if (ii < 0) ii = 0;                 // row 0 garbage (never scanned)
        const float4* x1 = (const float4*)(prow + (size_t)(ii + 1) * D + d0);
        const float4* x0 = (const float4*)(prow + (size_t)ii * D + d0);
        float4 h1 = x1[0], h0 = x0[0], g1 = x1[1], g0 = x0[1];
        bf16x8 f;
        f[0] = f2bf(h1.x - h0.x); f[1] = f2bf(h1.y - h0.y);
        f[2] = f2bf(h1.z - h0.z); f[3] = f2bf(h1.w - h0.w);
        f[4] = f2bf(g1.x - g0.x); f[5] = f2bf(g1.y - g0.y);
        f[6] = f2bf(g1.z - g0.z); f[7] = f2bf(g1.w - g0.w);
        return f;
    };

    const int rot = (l >> 2) & 7;           // read-side rotation (0-conflict)
    float* wbase = sinc + kh * 2048;

    // persistent per-lane LDS byte addresses for the 8 swizzled e-reads
    unsigned eaddr[8];
    #pragma unroll
    for (int m = 0; m < 8; ++m)
        eaddr[m] = (unsigned)(size_t)((const char*)sinc
                                      + (8 * l + ((m + rot) & 7)) * 4);

    // ---- scan state ----
    float s[8];
    #pragma unroll
    for (int m = 0; m < 8; ++m) s[m] = 0.0f;   // K[0][j] = 1 = B + 0
    float B = 1.0f;

    v2f ghA[8], ghB[8];
    float eA[8], eB[8];

    const f32x16 accC = {-1.f,-1.f,-1.f,-1.f,-1.f,-1.f,-1.f,-1.f,
                         -1.f,-1.f,-1.f,-1.f,-1.f,-1.f,-1.f,-1.f};

#define SBAR() __builtin_amdgcn_sched_barrier(0)
#define LWAIT() asm volatile("s_waitcnt lgkmcnt(0)" ::: "memory")

#define PREFA(BUF, RR) do {                                                   \
        asm volatile("ds_read_b32 %0, %1 offset:%c2"                          \
                     : "=v"(BUF[0]) : "v"(eaddr[0]), "i"((RR) * 2048));       \
        asm volatile("ds_read_b32 %0, %1 offset:%c2"                          \
                     : "=v"(BUF[1]) : "v"(eaddr[1]), "i"((RR) * 2048));       \
        asm volatile("ds_read_b32 %0, %1 offset:%c2"                          \
                     : "=v"(BUF[2]) : "v"(eaddr[2]), "i"((RR) * 2048));       \
        asm volatile("ds_read_b32 %0, %1 offset:%c2"                          \
                     : "=v"(BUF[3]) : "v"(eaddr[3]), "i"((RR) * 2048));       \
        asm volatile("ds_read_b32 %0, %1 offset:%c2"                          \
                     : "=v"(BUF[4]) : "v"(eaddr[4]), "i"((RR) * 2048));       \
        asm volatile("ds_read_b32 %0, %1 offset:%c2"                          \
                     : "=v"(BUF[5]) : "v"(eaddr[5]), "i"((RR) * 2048));       \
        asm volatile("ds_read_b32 %0, %1 offset:%c2"                          \
                     : "=v"(BUF[6]) : "v"(eaddr[6]), "i"((RR) * 2048));       \
        asm volatile("ds_read_b32 %0, %1 offset:%c2"                          \
                     : "=v"(BUF[7]) : "v"(eaddr[7]), "i"((RR) * 2048));       \
    } while (0)

#define GHBUILD(GH, E) do {                                                   \
        float p0_ = E[0] + 1.0f;  p0_ = lane0 ? 0.0f : p0_;                   \
        float c0_ = lane0 ? 0.0f : s[0];                                      \
        GH[0][0] = p0_; GH[0][1] = c0_;                                       \
        _Pragma("unroll")                                                     \
        for (int m_ = 1; m_ < 8; ++m_) {                                      \
            v2f pc_;                                                          \
            pc_[0] = E[m_] + 1.0f;                                            \
            pc_[1] = fmaf(s[m_ - 1], E[m_], s[m_]);                          \
            GH[m_] = GH[m_ - 1] + pc_;                                        \
        }                                                                     \
    } while (0)

#define SFMA(GH) do {                                                         \
        _Pragma("unroll")                                                     \
        for (int m_ = 0; m_ < 8; ++m_)                                        \
            s[m_] = fmaf(B, GH[m_][0], GH[m_][1]);                            \
    } while (0)

// hand-scheduled row step: consume GHC + e=EN (waited at head); build GHN;
// prefetch EP <- tile row RP. DPP chain interleaved with independent slots.
#define DSTEPI(GHC, GHN, EN, EP, RP) do {                                     \
        LWAIT();                                                              \
        SBAR();                                                               \
        float s7_ = fmaf(B, GHC[7][0], GHC[7][1]);                            \
        float x_ = s7_; int t_;                                               \
        t_ = __builtin_amdgcn_update_dpp(0, __float_as_int(x_), 0x111, 0xF, 0xF, true); \
        SBAR();                                                               \
        s[7] = s7_;                                                           \
        s[0] = fmaf(B, GHC[0][0], GHC[0][1]);                                 \
        s[1] = fmaf(B, GHC[1][0], GHC[1][1]);                                 \
        s[2] = fmaf(B, GHC[2][0], GHC[2][1]);                                 \
        s[3] = fmaf(B, GHC[3][0], GHC[3][1]);                                 \
        s[4] = fmaf(B, GHC[4][0], GHC[4][1]);                                 \
        s[5] = fmaf(B, GHC[5][0], GHC[5][1]);                                 \
        s[6] = fmaf(B, GHC[6][0], GHC[6][1]);                                 \
        SBAR();                                                               \
        x_ += __int_as_float(t_);                                             \
        t_ = __builtin_amdgcn_update_dpp(0, __float_as_int(x_), 0x112, 0xF, 0xF, true); \
        SBAR();                                                               \
        v2f pc1_, pc2_, pc3_, pc4_;                                           \
        pc1_[0] = EN[1] + 1.0f; pc1_[1] = fmaf(s[0], EN[1], s[1]);            \
        pc2_[0] = EN[2] + 1.0f; pc2_[1] = fmaf(s[1], EN[2], s[2]);            \
        pc3_[0] = EN[3] + 1.0f; pc3_[1] = fmaf(s[2], EN[3], s[3]);            \
        pc4_[0] = EN[4] + 1.0f; pc4_[1] = fmaf(s[3], EN[4], s[4]);            \
        SBAR();                                                               \
        x_ += __int_as_float(t_);                                             \
        t_ = __builtin_amdgcn_update_dpp(0, __float_as_int(x_), 0x114, 0xF, 0xF, true); \
        SBAR();                                                               \
        v2f pc5_, pc6_, pc7_;                                                 \
        pc5_[0] = EN[5] + 1.0f; pc5_[1] = fmaf(s[4], EN[5], s[5]);            \
        pc6_[0] = EN[6] + 1.0f; pc6_[1] = fmaf(s[5], EN[6], s[6]);            \
        pc7_[0] = EN[7] + 1.0f; pc7_[1] = fmaf(s[6], EN[7], s[7]);            \
        { float gp_ = EN[0] + 1.0f; gp_ = lane0 ? 0.0f : gp_;                 \
          float gc_ = lane0 ? 0.0f : s[0];                                    \
          GHN[0][0] = gp_; GHN[0][1] = gc_; }                                 \
        SBAR();                                                               \
        x_ += __int_as_float(t_);                                             \
        t_ = __builtin_amdgcn_update_dpp(0, __float_as_int(x_), 0x118, 0xF, 0xF, true); \
        SBAR();                                                               \
        GHN[1] = GHN[0] + pc1_;                                               \
        GHN[2] = GHN[1] + pc2_;                                               \
        GHN[3] = GHN[2] + pc3_;                                               \
        GHN[4] = GHN[3] + pc4_;                                               \
        SBAR();                                                               \
        x_ += __int_as_float(t_);                                             \
        t_ = __builtin_amdgcn_update_dpp(0, __float_as_int(x_), 0x142, 0xA, 0xF, false); \
        SBAR();                                                               \
        GHN[5] = GHN[4] + pc5_;                                               \
        GHN[6] = GHN[5] + pc6_;                                               \
        GHN[7] = GHN[6] + pc7_;                                               \
        PREFA(EP, RP);                                                        \
        SBAR();                                                               \
        x_ += __int_as_float(t_);                                             \
        t_ = __builtin_amdgcn_update_dpp(0, __float_as_int(x_), 0x143, 0xC, 0xF, false); \
        SBAR();                                                               \
        x_ += __int_as_float(t_);                                             \
        B = 1.0f + (x_ - s7_);                                                \
    } while (0)

#define TAILI(GHC) do {                                                       \
        LWAIT();                                                              \
        SBAR();                                                               \
        SFMA(GHC);                                                            \
        float S_ = s[7];                                                      \
        float W_ = wave_iscan(S_);                                            \
        B = 1.0f + (W_ - S_);                                                 \
    } while (0)

#define SCAN_BLOCK(FROM) do {                                                 \
        PREFA(eA, (FROM));                                                    \
        LWAIT();                                                              \
        GHBUILD(ghA, eA);                                                     \
        PREFA(eB, (FROM) + 1);                                                \
        _Pragma("unroll")                                                     \
        for (int r_ = (FROM); r_ <= 30; ++r_) {                               \
            const int rp_ = (r_ + 2 <= 31) ? r_ + 2 : 31;                     \
            if (((r_ - (FROM)) & 1) == 0) DSTEPI(ghA, ghB, eB, eA, rp_);      \
            else                          DSTEPI(ghB, ghA, eA, eB, rp_);      \
        }                                                                     \
        if (((31 - (FROM)) & 1) == 0) TAILI(ghA);                             \
        else                          TAILI(ghB);                             \
    } while (0)

    bf16x8 Acur = loadA(0);

    for (int b = 0; b < 16; ++b) {
        // ---- GEMM phase: (inc-1) rows 32b..32b+31, all 512 cols ----
        #pragma unroll
        for (int n = 0; n < 16; ++n) {
            f32x16 acc = __builtin_amdgcn_mfma_f32_32x32x16_bf16(Acur, Bf[n], accC, 0, 0, 0);
            float* p = wbase + 32 * n + (lm & ~7) + (((l & 7) + n) & 7);
            #pragma unroll
            for (int r = 0; r < 16; ++r)
                p[(r & 3) * 512 + (r >> 2) * 4096] = acc[r];
        }
        if (b < 15) Acur = loadA(b + 1);    // global prefetch under the scan

        // ---- scan phase (block 0 skips grid row 0) ----
        if (b == 0) SCAN_BLOCK(1);
        else        SCAN_BLOCK(0);
    }

#undef SCAN_BLOCK
#undef TAILI
#undef DSTEPI
#undef SFMA
#undef GHBUILD
#undef PREFA
#undef LWAIT
#undef SBAR

    // K[511][511] = lane 63: B + s[7]
    if (l == 63) out[idx] = B + s[7];
}

__global__ void sig_reduce_kernel(const float* __restrict__ ws,
                                  float* __restrict__ out) {
    const int a = threadIdx.x;  // 128 threads
    float v = ws[a] + ws[128 + a] - 2.0f * ws[256 + a];
    #pragma unroll
    for (int off = 32; off >= 1; off >>= 1) v += __shfl_down(v, off, 64);
    __shared__ float partial[2];
    if ((a & 63) == 0) partial[a >> 6] = v;
    __syncthreads();
    if (a == 0) out[0] = (partial[0] + partial[1]) * (1.0f / 128.0f);
}

extern "C" void kernel_launch(void* const* d_in, const int* in_sizes, int n_in,
                              void* d_out, int out_size, void* d_ws, size_t ws_size,
                              hipStream_t stream) {
    const float* X = (const float*)d_in[0];
    const float* Y = (const float*)d_in[1];
    float* out = (float*)d_out;
    float* ws  = (float*)d_ws;   // 384 floats: [pair*128 + a]

    sig_pde_kernel<<<dim3(384), dim3(64), 0, stream>>>(X, Y, ws);
    sig_reduce_kernel<<<dim3(1), dim3(128), 0, stream>>>(ws, out);
}

// Round 20
// 83.441 us; speedup vs baseline: 1.8860x; 1.0913x over previous
//
#include <hip/hip_runtime.h>

#define D 16

typedef short bf16x8 __attribute__((ext_vector_type(8)));
typedef float f32x16 __attribute__((ext_vector_type(16)));
typedef float v2f __attribute__((ext_vector_type(2)));

// ---- DPP helpers (wave64), verified rounds 8-18 ----
template<int CTRL, int RMASK, bool BC>
__device__ __forceinline__ float dpp_add(float x) {
    int t = __builtin_amdgcn_update_dpp(0, __float_as_int(x), CTRL, RMASK, 0xF, BC);
    return x + __int_as_float(t);
}
__device__ __forceinline__ float wave_iscan(float x) {
    x = dpp_add<0x111, 0xF, true >(x);   // row_shr:1
    x = dpp_add<0x112, 0xF, true >(x);   // row_shr:2
    x = dpp_add<0x114, 0xF, true >(x);   // row_shr:4
    x = dpp_add<0x118, 0xF, true >(x);   // row_shr:8
    x = dpp_add<0x142, 0xA, false>(x);   // row_bcast:15
    x = dpp_add<0x143, 0xC, false>(x);   // row_bcast:31
    return x;
}

// f32 -> bf16 round-to-nearest-even
__device__ __forceinline__ short f2bf(float f) {
    unsigned u = __float_as_uint(f);
    unsigned r = u + 0x7FFFu + ((u >> 16) & 1u);
    return (short)(r >> 16);
}

// One wave per (pair,batch); r15 structure with a COUNTED-WAIT scan pipeline:
// the 8 ds_reads for row r+2 issue at the TOP of row r's body, and the wait
// is s_waitcnt lgkmcnt(8) (T4 pattern) -- it returns as soon as row r+1's
// buffer is complete (the 8 newest outstanding ops are the just-issued
// prefetch), so the LDS pipe never drains and no latency is exposed.
__global__ __launch_bounds__(64, 1)
void sig_pde_kernel(const float* __restrict__ X, const float* __restrict__ Y,
                    float* __restrict__ out) {
    __shared__ float sinc[32 * 512];        // 64 KB (inc-1) block, swizzled

    const int idx  = blockIdx.x;
    const int pair = idx >> 7;              // 0: XX, 1: YY, 2: XY
    const int a    = idx & 127;
    const float* Pp = (pair == 1) ? Y : X;  // row operand (dX)
    const float* Qp = (pair == 0) ? X : Y;  // col operand (dY)
    const float* prow = Pp + (size_t)a * 512 * D;
    const float* qrow = Qp + (size_t)a * 512 * D;

    const int l  = threadIdx.x;
    const int lm = l & 31;
    const int kh = l >> 5;                  // K-half of the fragment
    const int d0 = kh * 8;                  // this lane's dim offset
    const bool lane0 = (l == 0);

    // ---- B fragments: 16 column tiles of dY, resident in registers ----
    bf16x8 Bf[16];
    #pragma unroll
    for (int n = 0; n < 16; ++n) {
        int jj = 32 * n + lm - 1;
        if (jj < 0) jj = 0;                 // col 0 garbage (masked in scan)
        const float4* y1 = (const float4*)(qrow + (size_t)(jj + 1) * D + d0);
        const float4* y0 = (const float4*)(qrow + (size_t)jj * D + d0);
        float4 h1 = y1[0], h0 = y0[0], g1 = y1[1], g0 = y0[1];
        bf16x8 f;
        f[0] = f2bf(h1.x - h0.x); f[1] = f2bf(h1.y - h0.y);
        f[2] = f2bf(h1.z - h0.z); f[3] = f2bf(h1.w - h0.w);
        f[4] = f2bf(g1.x - g0.x); f[5] = f2bf(g1.y - g0.y);
        f[6] = f2bf(g1.z - g0.z); f[7] = f2bf(g1.w - g0.w);
        Bf[n] = f;
    }

    auto loadA = [&](int b) -> bf16x8 {
        int ii = 32 * b + lm - 1;
        if (ii < 0) ii = 0;                 // row 0 garbage (never scanned)
        const float4* x1 = (const float4*)(prow + (size_t)(ii + 1) * D + d0);
        const float4* x0 = (const float4*)(prow + (size_t)ii * D + d0);
        float4 h1 = x1[0], h0 = x0[0], g1 = x1[1], g0 = x0[1];
        bf16x8 f;
        f[0] = f2bf(h1.x - h0.x); f[1] = f2bf(h1.y - h0.y);
        f[2] = f2bf(h1.z - h0.z); f[3] = f2bf(h1.w - h0.w);
        f[4] = f2bf(g1.x - g0.x); f[5] = f2bf(g1.y - g0.y);
        f[6] = f2bf(g1.z - g0.z); f[7] = f2bf(g1.w - g0.w);
        return f;
    };

    const int rot = (l >> 2) & 7;           // read-side rotation (0-conflict)
    float* wbase = sinc + kh * 2048;

    // persistent per-lane LDS byte addresses for the 8 swizzled e-reads
    unsigned eaddr[8];
    #pragma unroll
    for (int m = 0; m < 8; ++m)
        eaddr[m] = (unsigned)(size_t)((const char*)sinc
                                      + (8 * l + ((m + rot) & 7)) * 4);

    // ---- scan state ----
    float s[8];
    #pragma unroll
    for (int m = 0; m < 8; ++m) s[m] = 0.0f;   // K[0][j] = 1 = B + 0
    float B = 1.0f;

    v2f ghA[8], ghB[8];
    float eA[8], eB[8];

    const f32x16 accC = {-1.f,-1.f,-1.f,-1.f,-1.f,-1.f,-1.f,-1.f,
                         -1.f,-1.f,-1.f,-1.f,-1.f,-1.f,-1.f,-1.f};

// counted wait: everything except the 8 newest DS ops (the prefetch just
// issued) is complete -> previous row's buffer ready, pipe never drains.
#define WAIT8() do {                                                          \
        asm volatile("s_waitcnt lgkmcnt(8)" ::: "memory");                    \
        __builtin_amdgcn_sched_barrier(0);                                    \
    } while (0)

#define PREFA(BUF, RR) do {                                                   \
        asm volatile("ds_read_b32 %0, %1 offset:%c2"                          \
                     : "=v"(BUF[0]) : "v"(eaddr[0]), "i"((RR) * 2048));       \
        asm volatile("ds_read_b32 %0, %1 offset:%c2"                          \
                     : "=v"(BUF[1]) : "v"(eaddr[1]), "i"((RR) * 2048));       \
        asm volatile("ds_read_b32 %0, %1 offset:%c2"                          \
                     : "=v"(BUF[2]) : "v"(eaddr[2]), "i"((RR) * 2048));       \
        asm volatile("ds_read_b32 %0, %1 offset:%c2"                          \
                     : "=v"(BUF[3]) : "v"(eaddr[3]), "i"((RR) * 2048));       \
        asm volatile("ds_read_b32 %0, %1 offset:%c2"                          \
                     : "=v"(BUF[4]) : "v"(eaddr[4]), "i"((RR) * 2048));       \
        asm volatile("ds_read_b32 %0, %1 offset:%c2"                          \
                     : "=v"(BUF[5]) : "v"(eaddr[5]), "i"((RR) * 2048));       \
        asm volatile("ds_read_b32 %0, %1 offset:%c2"                          \
                     : "=v"(BUF[6]) : "v"(eaddr[6]), "i"((RR) * 2048));       \
        asm volatile("ds_read_b32 %0, %1 offset:%c2"                          \
                     : "=v"(BUF[7]) : "v"(eaddr[7]), "i"((RR) * 2048));       \
    } while (0)

#define GHBUILD(GH, E) do {                                                   \
        float p0_ = E[0] + 1.0f;  p0_ = lane0 ? 0.0f : p0_;                   \
        float c0_ = lane0 ? 0.0f : s[0];                                      \
        GH[0][0] = p0_; GH[0][1] = c0_;                                       \
        _Pragma("unroll")                                                     \
        for (int m_ = 1; m_ < 8; ++m_) {                                      \
            v2f pc_;                                                          \
            pc_[0] = E[m_] + 1.0f;                                            \
            pc_[1] = fmaf(s[m_ - 1], E[m_], s[m_]);                          \
            GH[m_] = GH[m_ - 1] + pc_;                                        \
        }                                                                     \
    } while (0)

#define SFMA(GH) do {                                                         \
        _Pragma("unroll")                                                     \
        for (int m_ = 0; m_ < 8; ++m_)                                        \
            s[m_] = fmaf(B, GH[m_][0], GH[m_][1]);                            \
    } while (0)

// row step: prefetch row RP into EFREE (top), counted wait, consume GHC,
// build GHN (row r+1) from EREADY (its reads are now complete).
#define STEP1(GHC, GHN, EFREE, EREADY, RP) do {                               \
        PREFA(EFREE, RP);                                                     \
        WAIT8();                                                              \
        SFMA(GHC);                                                            \
        float S_ = s[7];                                                      \
        float W_ = wave_iscan(S_);                                            \
        GHBUILD(GHN, EREADY);                                                 \
        B = 1.0f + (W_ - S_);                                                 \
    } while (0)

// scan tile rows FROM..31 (at block boundary the final GH build consumes a
// duplicated row-31 buffer; that GH is overwritten by the next prologue
// before any use -- provably dead).
#define SCAN_BLOCK(FROM) do {                                                 \
        PREFA(eA, (FROM));                                                    \
        PREFA(eB, (FROM) + 1);                                                \
        WAIT8();                    /* eA ready (eB is the newest 8) */       \
        GHBUILD(ghA, eA);                                                     \
        _Pragma("unroll")                                                     \
        for (int r_ = (FROM); r_ <= 31; ++r_) {                               \
            const int rp_ = (r_ + 2 <= 31) ? r_ + 2 : 31;                     \
            if (((r_ - (FROM)) & 1) == 0) STEP1(ghA, ghB, eA, eB, rp_);       \
            else                          STEP1(ghB, ghA, eB, eA, rp_);       \
        }                                                                     \
    } while (0)

    bf16x8 Acur = loadA(0);

    for (int b = 0; b < 16; ++b) {
        // ---- GEMM phase: (inc-1) rows 32b..32b+31, all 512 cols ----
        #pragma unroll
        for (int n = 0; n < 16; ++n) {
            f32x16 acc = __builtin_amdgcn_mfma_f32_32x32x16_bf16(Acur, Bf[n], accC, 0, 0, 0);
            float* p = wbase + 32 * n + (lm & ~7) + (((l & 7) + n) & 7);
            #pragma unroll
            for (int r = 0; r < 16; ++r)
                p[(r & 3) * 512 + (r >> 2) * 4096] = acc[r];
        }
        if (b < 15) Acur = loadA(b + 1);    // global prefetch under the scan

        // ---- scan phase (block 0 skips grid row 0) ----
        if (b == 0) SCAN_BLOCK(1);
        else        SCAN_BLOCK(0);
    }

#undef SCAN_BLOCK
#undef STEP1
#undef SFMA
#undef GHBUILD
#undef PREFA
#undef WAIT8

    // K[511][511] = lane 63: B + s[7]
    if (l == 63) out[idx] = B + s[7];
}

__global__ void sig_reduce_kernel(const float* __restrict__ ws,
                                  float* __restrict__ out) {
    const int a = threadIdx.x;  // 128 threads
    float v = ws[a] + ws[128 + a] - 2.0f * ws[256 + a];
    #pragma unroll
    for (int off = 32; off >= 1; off >>= 1) v += __shfl_down(v, off, 64);
    __shared__ float partial[2];
    if ((a & 63) == 0) partial[a >> 6] = v;
    __syncthreads();
    if (a == 0) out[0] = (partial[0] + partial[1]) * (1.0f / 128.0f);
}

extern "C" void kernel_launch(void* const* d_in, const int* in_sizes, int n_in,
                              void* d_out, int out_size, void* d_ws, size_t ws_size,
                              hipStream_t stream) {
    const float* X = (const float*)d_in[0];
    const float* Y = (const float*)d_in[1];
    float* out = (float*)d_out;
    float* ws  = (float*)d_ws;   // 384 floats: [pair*128 + a]

    sig_pde_kernel<<<dim3(384), dim3(64), 0, stream>>>(X, Y, ws);
    sig_reduce_kernel<<<dim3(1), dim3(128), 0, stream>>>(ws, out);
}